// Round 2
// baseline (545.987 us; speedup 1.0000x reference)
//
#include <hip/hip_runtime.h>
#include <hip/hip_bf16.h>

#define TT 2048
#define BB 8
#define DD 128
#define HH 4
#define BT (BB*TT)
#define BH (BB*HH)
#define SCALE 0.1767766952966369f

typedef __attribute__((ext_vector_type(8))) short short8;
typedef __attribute__((ext_vector_type(4))) float f32x4;
typedef __hip_bfloat16 bf16;

#define MFMA16(a,b,c) __builtin_amdgcn_mfma_f32_16x16x32_bf16(a,b,c,0,0,0)

static __device__ inline short8 ldg8(const bf16* p) {
  return *reinterpret_cast<const short8*>(p);
}
static __device__ inline float b2f(bf16 x) { return __bfloat162float(x); }
static __device__ inline short f2bs(float x) {
  bf16 h = __float2bfloat16(x);
  return *reinterpret_cast<short*>(&h);
}

// ---------------- Kernel 1: h = hawkes@Wp^T+bp ; q,k,v projections ----------
// Inputs f32. q,k stored bf16 (B,H,T,32); v stored transposed bf16 (B,H,32,T).
__global__ __launch_bounds__(256) void proj_kernel(
    const float* __restrict__ lob, const float* __restrict__ hawkes,
    const float* __restrict__ Wp, const float* __restrict__ bp,
    const float* __restrict__ Win, const float* __restrict__ binp,
    bf16* __restrict__ qg, bf16* __restrict__ kg, bf16* __restrict__ vtg) {
  __shared__ bf16  sWin[128*385];   // [d][c] transposed, pad 385
  __shared__ float sWp[32*129];     // [j][c] transposed, pad 129
  __shared__ float sBias[512];      // [0..383]=bin_, [384..511]=bp
  __shared__ float sRow[288];       // lob[0..127], hawkes[128..159], h[160..287]
  int tid = threadIdx.x;
  for (int i = tid; i < 384*128; i += 256) {
    int c = i >> 7, d = i & 127;
    sWin[d*385 + c] = __float2bfloat16(Win[i]);
  }
  for (int i = tid; i < 128*32; i += 256) {
    int c = i >> 5, j = i & 31;
    sWp[j*129 + c] = Wp[i];
  }
  for (int i = tid; i < 384; i += 256) sBias[i] = binp[i];
  if (tid < 128) sBias[384 + tid] = bp[tid];
  __syncthreads();
  for (int r = 0; r < 64; ++r) {
    int row = blockIdx.x*64 + r;          // b*T + t
    if (tid < 128)      sRow[tid] = lob[(size_t)row*128 + tid];
    else if (tid < 160) sRow[tid] = hawkes[(size_t)row*32 + (tid-128)];
    __syncthreads();
    int b = row >> 11, t = row & 2047;
    if (tid < 128) {                      // h
      float acc = sBias[384 + tid];
      #pragma unroll
      for (int j = 0; j < 32; ++j) acc += sRow[128 + j] * sWp[j*129 + tid];
      sRow[160 + tid] = acc;
    } else {                              // q
      int c = tid - 128;
      float acc = sBias[c];
      #pragma unroll 8
      for (int d = 0; d < 128; ++d) acc += sRow[d] * b2f(sWin[d*385 + c]);
      int h = c >> 5, dd = c & 31;
      qg[(((size_t)(b*HH + h))*TT + t)*32 + dd] = __float2bfloat16(acc);
    }
    __syncthreads();
    {                                     // k (tid<128) / v (tid>=128)
      int c = tid & 127;
      int wc = 128 + (tid >> 7)*128 + c;
      float acc = sBias[wc];
      #pragma unroll 8
      for (int d = 0; d < 128; ++d) acc += sRow[160 + d] * b2f(sWin[d*385 + wc]);
      int h = c >> 5, dd = c & 31;
      if (tid < 128) kg[(((size_t)(b*HH + h))*TT + t)*32 + dd] = __float2bfloat16(acc);
      else           vtg[(((size_t)(b*HH + h))*32 + dd)*TT + t] = __float2bfloat16(acc);
    }
    __syncthreads();
  }
}

// ---------------- Kernel 2: softmax denominators l[b,h,t] -------------------
__global__ __launch_bounds__(64) void lsum_kernel(const bf16* __restrict__ qg,
    const bf16* __restrict__ kg, float* __restrict__ lg) {
  int bh = blockIdx.x >> 6, qt = blockIdx.x & 63;
  int lane = threadIdx.x;
  int lr = lane & 15, lq = lane >> 4;
  const bf16* qp = qg + ((size_t)(bh*TT) + qt*32)*32;
  short8 a0 = ldg8(qp + lr*32 + lq*8);
  short8 a1 = ldg8(qp + (16+lr)*32 + lq*8);
  float rs[2][4] = {{0.f,0.f,0.f,0.f},{0.f,0.f,0.f,0.f}};
  for (int kt = 0; kt < 64; ++kt) {
    const bf16* kp = kg + ((size_t)(bh*TT) + kt*32)*32;
    short8 b0 = ldg8(kp + lr*32 + lq*8);
    short8 b1 = ldg8(kp + (16+lr)*32 + lq*8);
    f32x4 z = {0.f,0.f,0.f,0.f};
    f32x4 s00 = MFMA16(a0, b0, z);
    f32x4 s01 = MFMA16(a0, b1, z);
    f32x4 s10 = MFMA16(a1, b0, z);
    f32x4 s11 = MFMA16(a1, b1, z);
    #pragma unroll
    for (int r = 0; r < 4; ++r) {
      rs[0][r] += __expf(s00[r]*SCALE) + __expf(s01[r]*SCALE);
      rs[1][r] += __expf(s10[r]*SCALE) + __expf(s11[r]*SCALE);
    }
  }
  #pragma unroll
  for (int m = 1; m <= 8; m <<= 1) {
    #pragma unroll
    for (int mt = 0; mt < 2; ++mt)
      #pragma unroll
      for (int r = 0; r < 4; ++r)
        rs[mt][r] += __shfl_xor(rs[mt][r], m, 64);
  }
  if (lr == 0) {
    #pragma unroll
    for (int mt = 0; mt < 2; ++mt)
      #pragma unroll
      for (int r = 0; r < 4; ++r)
        lg[(size_t)bh*TT + qt*32 + mt*16 + lq*4 + r] = rs[mt][r];
  }
}

// ---------------- Kernel 3: attention (recompute, normalize, attn_w, PV) ----
// block = (b, 32-row q-tile); wave w = head w.
__global__ __launch_bounds__(256) void attn_kernel(const bf16* __restrict__ qg,
    const bf16* __restrict__ kg, const bf16* __restrict__ vtg,
    const float* __restrict__ lg, float* __restrict__ attn_out,
    float* __restrict__ ctxg) {
  int b = blockIdx.x >> 6, qt = blockIdx.x & 63;
  int head = threadIdx.x >> 6, lane = threadIdx.x & 63;
  int lr = lane & 15, lq = lane >> 4;
  int bh = b*HH + head;
  __shared__ float plds[4][32*33];
  const bf16* qp = qg + ((size_t)(bh*TT) + qt*32)*32;
  short8 a0 = ldg8(qp + lr*32 + lq*8);
  short8 a1 = ldg8(qp + (16+lr)*32 + lq*8);
  float rinv[2][4];
  #pragma unroll
  for (int mt = 0; mt < 2; ++mt)
    #pragma unroll
    for (int r = 0; r < 4; ++r)
      rinv[mt][r] = 1.0f / lg[(size_t)bh*TT + qt*32 + mt*16 + lq*4 + r];
  f32x4 z = {0.f,0.f,0.f,0.f};
  f32x4 ctxa00 = z, ctxa01 = z, ctxa10 = z, ctxa11 = z;
  for (int kt = 0; kt < 64; ++kt) {
    const bf16* kp = kg + ((size_t)(bh*TT) + kt*32)*32;
    short8 bk0 = ldg8(kp + lr*32 + lq*8);
    short8 bk1 = ldg8(kp + (16+lr)*32 + lq*8);
    const bf16* vp = vtg + ((size_t)(bh*32))*TT + kt*32;
    short8 bv0 = ldg8(vp + (size_t)lr*TT + lq*8);
    short8 bv1 = ldg8(vp + (size_t)(16+lr)*TT + lq*8);
    f32x4 s00 = MFMA16(a0, bk0, z);
    f32x4 s01 = MFMA16(a0, bk1, z);
    f32x4 s10 = MFMA16(a1, bk0, z);
    f32x4 s11 = MFMA16(a1, bk1, z);
    #pragma unroll
    for (int r = 0; r < 4; ++r) {
      int row0 = lq*4 + r, row1 = row0 + 16;
      plds[head][row0*33 + lr]      = __expf(s00[r]*SCALE)*rinv[0][r];
      plds[head][row0*33 + 16+lr]   = __expf(s01[r]*SCALE)*rinv[0][r];
      plds[head][row1*33 + lr]      = __expf(s10[r]*SCALE)*rinv[1][r];
      plds[head][row1*33 + 16+lr]   = __expf(s11[r]*SCALE)*rinv[1][r];
    }
    __syncthreads();
    {   // attn_w = mean over heads, straight to global (f32)
      int rr = threadIdx.x >> 3, c0 = (threadIdx.x & 7)*4;
      float* dst = attn_out + ((size_t)(b*TT + qt*32 + rr))*TT + kt*32 + c0;
      #pragma unroll
      for (int i = 0; i < 4; ++i) {
        dst[i] = 0.25f*(plds[0][rr*33+c0+i] + plds[1][rr*33+c0+i]
                      + plds[2][rr*33+c0+i] + plds[3][rr*33+c0+i]);
      }
    }
    // P: C-layout -> A-layout via LDS, convert to bf16
    short8 ap0, ap1;
    #pragma unroll
    for (int j = 0; j < 8; ++j) {
      ap0[j] = f2bs(plds[head][lr*33 + lq*8 + j]);
      ap1[j] = f2bs(plds[head][(16+lr)*33 + lq*8 + j]);
    }
    ctxa00 = MFMA16(ap0, bv0, ctxa00);
    ctxa01 = MFMA16(ap0, bv1, ctxa01);
    ctxa10 = MFMA16(ap1, bv0, ctxa10);
    ctxa11 = MFMA16(ap1, bv1, ctxa11);
    __syncthreads();
  }
  #pragma unroll
  for (int r = 0; r < 4; ++r) {
    int row0 = lq*4 + r, row1 = row0 + 16;
    size_t base0 = ((size_t)(b*TT + qt*32 + row0))*128 + head*32;
    size_t base1 = ((size_t)(b*TT + qt*32 + row1))*128 + head*32;
    ctxg[base0 + lr]      = ctxa00[r];
    ctxg[base0 + 16 + lr] = ctxa01[r];
    ctxg[base1 + lr]      = ctxa10[r];
    ctxg[base1 + 16 + lr] = ctxa11[r];
  }
}

// ---------------- Kernel 4: out-proj + residual + LayerNorm -----------------
__global__ __launch_bounds__(256) void outln_kernel(const float* __restrict__ ctxg,
    const float* __restrict__ lob, const float* __restrict__ Wo,
    const float* __restrict__ bo, const float* __restrict__ gamma,
    const float* __restrict__ beta, float* __restrict__ outg) {
  __shared__ float sWo[128*129];   // [d][c] transposed, pad 129
  __shared__ float sP[384];        // bo, gamma, beta
  __shared__ float sCtx[4][128];
  __shared__ float sLob[4][128];
  int tid = threadIdx.x;
  for (int i = tid; i < 128*128; i += 256) {
    int c = i >> 7, d = i & 127;
    sWo[d*129 + c] = Wo[i];
  }
  if (tid < 128) {
    sP[tid] = bo[tid]; sP[128+tid] = gamma[tid]; sP[256+tid] = beta[tid];
  }
  __syncthreads();
  int wave = tid >> 6, lane = tid & 63;
  for (int it = 0; it < 8; ++it) {
    int row = blockIdx.x*32 + it*4 + wave;
    sCtx[wave][lane]    = ctxg[(size_t)row*128 + lane];
    sCtx[wave][64+lane] = ctxg[(size_t)row*128 + 64 + lane];
    sLob[wave][lane]    = lob[(size_t)row*128 + lane];
    sLob[wave][64+lane] = lob[(size_t)row*128 + 64 + lane];
    __syncthreads();
    float x0 = sP[lane] + sLob[wave][lane];
    float x1 = sP[64+lane] + sLob[wave][64+lane];
    #pragma unroll 8
    for (int d = 0; d < 128; ++d) {
      float cv = sCtx[wave][d];
      x0 += cv * sWo[d*129 + lane];
      x1 += cv * sWo[d*129 + 64 + lane];
    }
    float sum = x0 + x1;
    #pragma unroll
    for (int m = 1; m < 64; m <<= 1) sum += __shfl_xor(sum, m, 64);
    float mu = sum * (1.0f/128.0f);
    float d0 = x0 - mu, d1 = x1 - mu;
    float vs = d0*d0 + d1*d1;
    #pragma unroll
    for (int m = 1; m < 64; m <<= 1) vs += __shfl_xor(vs, m, 64);
    float rstd = rsqrtf(vs*(1.0f/128.0f) + 1e-5f);
    outg[(size_t)row*128 + lane]      = d0*rstd*sP[128+lane] + sP[256+lane];
    outg[(size_t)row*128 + 64 + lane] = d1*rstd*sP[192+lane] + sP[320+lane];
    __syncthreads();
  }
}

extern "C" void kernel_launch(void* const* d_in, const int* in_sizes, int n_in,
                              void* d_out, int out_size, void* d_ws, size_t ws_size,
                              hipStream_t stream) {
  const float* lob    = (const float*)d_in[0];
  const float* hawkes = (const float*)d_in[1];
  const float* Wp     = (const float*)d_in[2];
  const float* bp     = (const float*)d_in[3];
  const float* Win    = (const float*)d_in[4];
  const float* binp   = (const float*)d_in[5];
  const float* Wo     = (const float*)d_in[6];
  const float* bo     = (const float*)d_in[7];
  const float* gamma  = (const float*)d_in[8];
  const float* beta   = (const float*)d_in[9];
  float* outg = (float*)d_out;
  float* attn_out = outg + (size_t)BT*128;   // out (B,T,128) then attn_w (B,T,T)

  char* ws = (char*)d_ws;
  bf16*  qg   = (bf16*)(ws);                                   // 4 MB
  bf16*  kg   = (bf16*)(ws + (size_t)4*1024*1024);             // 4 MB
  bf16*  vtg  = (bf16*)(ws + (size_t)8*1024*1024);             // 4 MB (B,H,32,T)
  float* lg   = (float*)(ws + (size_t)12*1024*1024);           // 256 KB
  float* ctxg = (float*)(ws + (size_t)12*1024*1024 + 512*1024);// 8 MB

  proj_kernel<<<256, 256, 0, stream>>>(lob, hawkes, Wp, bp, Win, binp, qg, kg, vtg);
  lsum_kernel<<<BH*(TT/32), 64, 0, stream>>>(qg, kg, lg);
  attn_kernel<<<BB*(TT/32), 256, 0, stream>>>(qg, kg, vtg, lg, attn_out, ctxg);
  outln_kernel<<<512, 256, 0, stream>>>(ctxg, lob, Wo, bo, gamma, beta, outg);
}

// Round 3
// 304.021 us; speedup vs baseline: 1.7959x; 1.7959x over previous
//
#include <hip/hip_runtime.h>
#include <hip/hip_bf16.h>

#define TT 2048
#define BB 8
#define DD 128
#define HH 4
#define BT (BB*TT)
#define BH (BB*HH)
#define SCALE 0.1767766952966369f

typedef __attribute__((ext_vector_type(8))) short short8;
typedef __attribute__((ext_vector_type(4))) float f32x4;
typedef __hip_bfloat16 bf16;

#define MFMA16(a,b,c) __builtin_amdgcn_mfma_f32_16x16x32_bf16(a,b,c,0,0,0)

static __device__ inline short8 ldg8(const bf16* p) {
  return *reinterpret_cast<const short8*>(p);
}
static __device__ inline float b2f(bf16 x) { return __bfloat162float(x); }
static __device__ inline short f2bs(float x) {
  bf16 h = __float2bfloat16(x);
  return *reinterpret_cast<short*>(&h);
}
// load 8 contiguous f32 from global, convert to bf16 A/B-fragment
static __device__ inline short8 ldcvt8(const float* p) {
  f32x4 f0 = *reinterpret_cast<const f32x4*>(p);
  f32x4 f1 = *reinterpret_cast<const f32x4*>(p + 4);
  short8 r;
  #pragma unroll
  for (int i = 0; i < 4; ++i) { r[i] = f2bs(f0[i]); r[4+i] = f2bs(f1[i]); }
  return r;
}

// ---------------- Kernel 1: MFMA projections ----------------
// Block = 32 rows (b*T+t), 4 waves. h = hawkes@Wp^T+bp (K=32, 1 MFMA step),
// round-trip through LDS to A-layout; then q,k,v = {lob,h,h}@Win^T+bin_.
// q,k stored bf16 (B,H,T,32); v transposed via LDS -> bf16 (B,H,32,T).
__global__ __launch_bounds__(256) void proj_kernel(
    const float* __restrict__ lob, const float* __restrict__ hawkes,
    const float* __restrict__ Wp, const float* __restrict__ bp,
    const float* __restrict__ Win, const float* __restrict__ binp,
    bf16* __restrict__ qg, bf16* __restrict__ kg, bf16* __restrict__ vtg) {
  __shared__ bf16 hT[32*136];   // h tile [m][k], stride 136 (272B, 16B-aligned)
  __shared__ bf16 vT[128*40];   // v^T tile [c][t], stride 40 (80B, 16B-aligned)
  int tid = threadIdx.x;
  int wave = tid >> 6, lane = tid & 63;
  int lr = lane & 15, lq = lane >> 4;
  int r0 = blockIdx.x * 32;          // global row base (b*T + t), 32 | T
  int b  = r0 >> 11, t0 = r0 & 2047;
  f32x4 z = {0.f,0.f,0.f,0.f};

  // A-fragments: lob (2 mt x 4 kt), hawkes (2 mt)
  short8 alob[2][4], ahk[2];
  #pragma unroll
  for (int mt = 0; mt < 2; ++mt) {
    const float* lp = lob + (size_t)(r0 + mt*16 + lr)*128;
    #pragma unroll
    for (int kt = 0; kt < 4; ++kt) alob[mt][kt] = ldcvt8(lp + kt*32 + lq*8);
    ahk[mt] = ldcvt8(hawkes + (size_t)(r0 + mt*16 + lr)*32 + lq*8);
  }

  // Phase H: h tiles (8 N-tiles over 4 waves)
  for (int nt = wave; nt < 8; nt += 4) {
    int cn = nt*16;
    short8 bfrag = ldcvt8(Wp + (size_t)(cn + lr)*32 + lq*8);
    float bias = bp[cn + lr];
    #pragma unroll
    for (int mt = 0; mt < 2; ++mt) {
      f32x4 c = MFMA16(ahk[mt], bfrag, z);
      #pragma unroll
      for (int r = 0; r < 4; ++r)
        hT[(mt*16 + lq*4 + r)*136 + cn + lr] = __float2bfloat16(c[r] + bias);
    }
  }
  __syncthreads();

  // h A-fragments from LDS
  short8 ah[2][4];
  #pragma unroll
  for (int mt = 0; mt < 2; ++mt)
    #pragma unroll
    for (int kt = 0; kt < 4; ++kt)
      ah[mt][kt] = *reinterpret_cast<const short8*>(&hT[(mt*16 + lr)*136 + kt*32 + lq*8]);

  // Phase QKV: 24 N-tiles over 4 waves (each wave: 2 q, 2 k, 2 v)
  for (int nt = wave; nt < 24; nt += 4) {
    int which = nt >> 3;            // 0=q, 1=k, 2=v
    int c = (nt & 7)*16 + lr;       // output column within 128
    const float* wrow = Win + (size_t)(which*128 + c)*128;
    float bias = binp[which*128 + c];
    f32x4 acc0 = z, acc1 = z;
    #pragma unroll
    for (int kt = 0; kt < 4; ++kt) {
      short8 bfrag = ldcvt8(wrow + kt*32 + lq*8);
      if (which == 0) {
        acc0 = MFMA16(alob[0][kt], bfrag, acc0);
        acc1 = MFMA16(alob[1][kt], bfrag, acc1);
      } else {
        acc0 = MFMA16(ah[0][kt], bfrag, acc0);
        acc1 = MFMA16(ah[1][kt], bfrag, acc1);
      }
    }
    int head = c >> 5, dd = c & 31;
    #pragma unroll
    for (int mt = 0; mt < 2; ++mt) {
      f32x4 acc = mt ? acc1 : acc0;
      #pragma unroll
      for (int r = 0; r < 4; ++r) {
        int row = mt*16 + lq*4 + r;
        float val = acc[r] + bias;
        if (which == 0)
          qg[((size_t)(b*HH + head)*TT + t0 + row)*32 + dd] = __float2bfloat16(val);
        else if (which == 1)
          kg[((size_t)(b*HH + head)*TT + t0 + row)*32 + dd] = __float2bfloat16(val);
        else
          vT[c*40 + row] = __float2bfloat16(val);
      }
    }
  }
  __syncthreads();

  // v writeout: 128 dd-rows x 32 t, coalesced 16B stores
  {
    int dd = tid >> 1, half = tid & 1;
    int bh = b*HH + (dd >> 5);
    short8 s0 = *reinterpret_cast<const short8*>(&vT[dd*40 + half*16]);
    short8 s1 = *reinterpret_cast<const short8*>(&vT[dd*40 + half*16 + 8]);
    bf16* dst = vtg + ((size_t)bh*32 + (dd & 31))*TT + t0 + half*16;
    *reinterpret_cast<short8*>(dst) = s0;
    *reinterpret_cast<short8*>(dst + 8) = s1;
  }
}

// ---------------- Kernel 2: softmax denominators l[b,h,t] -------------------
__global__ __launch_bounds__(64) void lsum_kernel(const bf16* __restrict__ qg,
    const bf16* __restrict__ kg, float* __restrict__ lg) {
  int bh = blockIdx.x >> 6, qt = blockIdx.x & 63;
  int lane = threadIdx.x;
  int lr = lane & 15, lq = lane >> 4;
  const bf16* qp = qg + ((size_t)(bh*TT) + qt*32)*32;
  short8 a0 = ldg8(qp + lr*32 + lq*8);
  short8 a1 = ldg8(qp + (16+lr)*32 + lq*8);
  float rs[2][4] = {{0.f,0.f,0.f,0.f},{0.f,0.f,0.f,0.f}};
  for (int kt = 0; kt < 64; ++kt) {
    const bf16* kp = kg + ((size_t)(bh*TT) + kt*32)*32;
    short8 b0 = ldg8(kp + lr*32 + lq*8);
    short8 b1 = ldg8(kp + (16+lr)*32 + lq*8);
    f32x4 z = {0.f,0.f,0.f,0.f};
    f32x4 s00 = MFMA16(a0, b0, z);
    f32x4 s01 = MFMA16(a0, b1, z);
    f32x4 s10 = MFMA16(a1, b0, z);
    f32x4 s11 = MFMA16(a1, b1, z);
    #pragma unroll
    for (int r = 0; r < 4; ++r) {
      rs[0][r] += __expf(s00[r]*SCALE) + __expf(s01[r]*SCALE);
      rs[1][r] += __expf(s10[r]*SCALE) + __expf(s11[r]*SCALE);
    }
  }
  #pragma unroll
  for (int m = 1; m <= 8; m <<= 1) {
    #pragma unroll
    for (int mt = 0; mt < 2; ++mt)
      #pragma unroll
      for (int r = 0; r < 4; ++r)
        rs[mt][r] += __shfl_xor(rs[mt][r], m, 64);
  }
  if (lr == 0) {
    #pragma unroll
    for (int mt = 0; mt < 2; ++mt)
      #pragma unroll
      for (int r = 0; r < 4; ++r)
        lg[(size_t)bh*TT + qt*32 + mt*16 + lq*4 + r] = rs[mt][r];
  }
}

// ---------------- Kernel 3: attention (recompute, normalize, attn_w, PV) ----
__global__ __launch_bounds__(256) void attn_kernel(const bf16* __restrict__ qg,
    const bf16* __restrict__ kg, const bf16* __restrict__ vtg,
    const float* __restrict__ lg, float* __restrict__ attn_out,
    float* __restrict__ ctxg) {
  int b = blockIdx.x >> 6, qt = blockIdx.x & 63;
  int head = threadIdx.x >> 6, lane = threadIdx.x & 63;
  int lr = lane & 15, lq = lane >> 4;
  int bh = b*HH + head;
  __shared__ float plds[4][32*33];
  const bf16* qp = qg + ((size_t)(bh*TT) + qt*32)*32;
  short8 a0 = ldg8(qp + lr*32 + lq*8);
  short8 a1 = ldg8(qp + (16+lr)*32 + lq*8);
  float rinv[2][4];
  #pragma unroll
  for (int mt = 0; mt < 2; ++mt)
    #pragma unroll
    for (int r = 0; r < 4; ++r)
      rinv[mt][r] = 1.0f / lg[(size_t)bh*TT + qt*32 + mt*16 + lq*4 + r];
  f32x4 z = {0.f,0.f,0.f,0.f};
  f32x4 ctxa00 = z, ctxa01 = z, ctxa10 = z, ctxa11 = z;
  for (int kt = 0; kt < 64; ++kt) {
    const bf16* kp = kg + ((size_t)(bh*TT) + kt*32)*32;
    short8 bk0 = ldg8(kp + lr*32 + lq*8);
    short8 bk1 = ldg8(kp + (16+lr)*32 + lq*8);
    const bf16* vp = vtg + ((size_t)(bh*32))*TT + kt*32;
    short8 bv0 = ldg8(vp + (size_t)lr*TT + lq*8);
    short8 bv1 = ldg8(vp + (size_t)(16+lr)*TT + lq*8);
    f32x4 s00 = MFMA16(a0, bk0, z);
    f32x4 s01 = MFMA16(a0, bk1, z);
    f32x4 s10 = MFMA16(a1, bk0, z);
    f32x4 s11 = MFMA16(a1, bk1, z);
    #pragma unroll
    for (int r = 0; r < 4; ++r) {
      int row0 = lq*4 + r, row1 = row0 + 16;
      plds[head][row0*33 + lr]      = __expf(s00[r]*SCALE)*rinv[0][r];
      plds[head][row0*33 + 16+lr]   = __expf(s01[r]*SCALE)*rinv[0][r];
      plds[head][row1*33 + lr]      = __expf(s10[r]*SCALE)*rinv[1][r];
      plds[head][row1*33 + 16+lr]   = __expf(s11[r]*SCALE)*rinv[1][r];
    }
    __syncthreads();
    {   // attn_w = mean over heads, straight to global (f32)
      int rr = threadIdx.x >> 3, c0 = (threadIdx.x & 7)*4;
      float* dst = attn_out + ((size_t)(b*TT + qt*32 + rr))*TT + kt*32 + c0;
      #pragma unroll
      for (int i = 0; i < 4; ++i) {
        dst[i] = 0.25f*(plds[0][rr*33+c0+i] + plds[1][rr*33+c0+i]
                      + plds[2][rr*33+c0+i] + plds[3][rr*33+c0+i]);
      }
    }
    // P: C-layout -> A-layout via LDS, convert to bf16
    short8 ap0, ap1;
    #pragma unroll
    for (int j = 0; j < 8; ++j) {
      ap0[j] = f2bs(plds[head][lr*33 + lq*8 + j]);
      ap1[j] = f2bs(plds[head][(16+lr)*33 + lq*8 + j]);
    }
    ctxa00 = MFMA16(ap0, bv0, ctxa00);
    ctxa01 = MFMA16(ap0, bv1, ctxa01);
    ctxa10 = MFMA16(ap1, bv0, ctxa10);
    ctxa11 = MFMA16(ap1, bv1, ctxa11);
    __syncthreads();
  }
  #pragma unroll
  for (int r = 0; r < 4; ++r) {
    int row0 = lq*4 + r, row1 = row0 + 16;
    size_t base0 = ((size_t)(b*TT + qt*32 + row0))*128 + head*32;
    size_t base1 = ((size_t)(b*TT + qt*32 + row1))*128 + head*32;
    ctxg[base0 + lr]      = ctxa00[r];
    ctxg[base0 + 16 + lr] = ctxa01[r];
    ctxg[base1 + lr]      = ctxa10[r];
    ctxg[base1 + 16 + lr] = ctxa11[r];
  }
}

// ---------------- Kernel 4: out-proj + residual + LayerNorm -----------------
__global__ __launch_bounds__(256) void outln_kernel(const float* __restrict__ ctxg,
    const float* __restrict__ lob, const float* __restrict__ Wo,
    const float* __restrict__ bo, const float* __restrict__ gamma,
    const float* __restrict__ beta, float* __restrict__ outg) {
  __shared__ float sWo[128*129];   // [d][c] transposed, pad 129
  __shared__ float sP[384];        // bo, gamma, beta
  __shared__ float sCtx[4][128];
  __shared__ float sLob[4][128];
  int tid = threadIdx.x;
  for (int i = tid; i < 128*128; i += 256) {
    int c = i >> 7, d = i & 127;
    sWo[d*129 + c] = Wo[i];
  }
  if (tid < 128) {
    sP[tid] = bo[tid]; sP[128+tid] = gamma[tid]; sP[256+tid] = beta[tid];
  }
  __syncthreads();
  int wave = tid >> 6, lane = tid & 63;
  for (int it = 0; it < 8; ++it) {
    int row = blockIdx.x*32 + it*4 + wave;
    sCtx[wave][lane]    = ctxg[(size_t)row*128 + lane];
    sCtx[wave][64+lane] = ctxg[(size_t)row*128 + 64 + lane];
    sLob[wave][lane]    = lob[(size_t)row*128 + lane];
    sLob[wave][64+lane] = lob[(size_t)row*128 + 64 + lane];
    __syncthreads();
    float x0 = sP[lane] + sLob[wave][lane];
    float x1 = sP[64+lane] + sLob[wave][64+lane];
    #pragma unroll 8
    for (int d = 0; d < 128; ++d) {
      float cv = sCtx[wave][d];
      x0 += cv * sWo[d*129 + lane];
      x1 += cv * sWo[d*129 + 64 + lane];
    }
    float sum = x0 + x1;
    #pragma unroll
    for (int m = 1; m < 64; m <<= 1) sum += __shfl_xor(sum, m, 64);
    float mu = sum * (1.0f/128.0f);
    float d0 = x0 - mu, d1 = x1 - mu;
    float vs = d0*d0 + d1*d1;
    #pragma unroll
    for (int m = 1; m < 64; m <<= 1) vs += __shfl_xor(vs, m, 64);
    float rstd = rsqrtf(vs*(1.0f/128.0f) + 1e-5f);
    outg[(size_t)row*128 + lane]      = d0*rstd*sP[128+lane] + sP[256+lane];
    outg[(size_t)row*128 + 64 + lane] = d1*rstd*sP[192+lane] + sP[320+lane];
    __syncthreads();
  }
}

extern "C" void kernel_launch(void* const* d_in, const int* in_sizes, int n_in,
                              void* d_out, int out_size, void* d_ws, size_t ws_size,
                              hipStream_t stream) {
  const float* lob    = (const float*)d_in[0];
  const float* hawkes = (const float*)d_in[1];
  const float* Wp     = (const float*)d_in[2];
  const float* bp     = (const float*)d_in[3];
  const float* Win    = (const float*)d_in[4];
  const float* binp   = (const float*)d_in[5];
  const float* Wo     = (const float*)d_in[6];
  const float* bo     = (const float*)d_in[7];
  const float* gamma  = (const float*)d_in[8];
  const float* beta   = (const float*)d_in[9];
  float* outg = (float*)d_out;
  float* attn_out = outg + (size_t)BT*128;   // out (B,T,128) then attn_w (B,T,T)

  char* ws = (char*)d_ws;
  bf16*  qg   = (bf16*)(ws);                                   // 4 MB
  bf16*  kg   = (bf16*)(ws + (size_t)4*1024*1024);             // 4 MB
  bf16*  vtg  = (bf16*)(ws + (size_t)8*1024*1024);             // 4 MB (B,H,32,T)
  float* lg   = (float*)(ws + (size_t)12*1024*1024);           // 256 KB
  float* ctxg = (float*)(ws + (size_t)12*1024*1024 + 512*1024);// 8 MB

  proj_kernel<<<BT/32, 256, 0, stream>>>(lob, hawkes, Wp, bp, Win, binp, qg, kg, vtg);
  lsum_kernel<<<BH*(TT/32), 64, 0, stream>>>(qg, kg, lg);
  attn_kernel<<<BB*(TT/32), 256, 0, stream>>>(qg, kg, vtg, lg, attn_out, ctxg);
  outln_kernel<<<512, 256, 0, stream>>>(ctxg, lob, Wo, bo, gamma, beta, outg);
}